// Round 14
// baseline (57.902 us; speedup 1.0000x reference)
//
#include <hip/hip_runtime.h>
#include <hip/hip_bf16.h>
#include <stdint.h>

#define M_DIM 128
#define N_DIM 8192
#define K_DIM 8192
#define KP    4096      // packed int32 per weight row
#define NGRP  64
#define KSPLIT 8
#define KCHUNK (K_DIM / KSPLIT)   // 1024
#define BK    64
#define NSTEPS (KCHUNK / BK)      // 16

typedef __attribute__((ext_vector_type(8))) short bf16x8;
typedef __attribute__((ext_vector_type(4))) float f32x4;

__device__ __forceinline__ unsigned short f2bf(float f) {
  unsigned int u = __float_as_uint(f);
  return (unsigned short)((u + 0x7fffu + ((u >> 16) & 1u)) >> 16);
}

// x f32->bf16 cast AND out = bias prefill (same 1M-element range).
__global__ void xcast_kernel(const float* __restrict__ x, unsigned short* __restrict__ xb,
                             const float* __restrict__ bias, float* __restrict__ out) {
  int idx = (blockIdx.x * blockDim.x + threadIdx.x) * 8;
  const float4* xp = (const float4*)(x + idx);
  float4 a = xp[0], b = xp[1];
  uint4 o;
  o.x = (unsigned)f2bf(a.x) | ((unsigned)f2bf(a.y) << 16);
  o.y = (unsigned)f2bf(a.z) | ((unsigned)f2bf(a.w) << 16);
  o.z = (unsigned)f2bf(b.x) | ((unsigned)f2bf(b.y) << 16);
  o.w = (unsigned)f2bf(b.z) | ((unsigned)f2bf(b.w) << 16);
  *(uint4*)(xb + idx) = o;
  // out[idx..idx+7] = bias[col..col+7]  (N_DIM divides row stride, so col = idx&8191)
  int col = idx & (N_DIM - 1);
  float4 b0 = *(const float4*)(bias + col);
  float4 b1 = *(const float4*)(bias + col + 4);
  *(float4*)(out + idx) = b0;
  *(float4*)(out + idx + 4) = b1;
}

// R10-verbatim main loop (champion, 44.5us): both streams via global_load_lds,
// double-buffered 64KB LDS, counted vmcnt(8) + raw barriers (never drain),
// scales preloaded, full unroll. ONLY the epilogue changed: fp32 atomicAdd
// into out (fire-and-forget, L2-side) replaces bf16 partial stores + reduce.
__global__ __launch_bounds__(256, 2)
void gemm_kernel(const unsigned short* __restrict__ xb,
                 const int* __restrict__ wq,
                 const float* __restrict__ scale,
                 const float* __restrict__ zpt,
                 float* __restrict__ out)
{
  __shared__ uint4 xtile[2][1024];   // 2 x 16 KB  (128 rows x 8 chunks, swizzled)
  __shared__ uint4 wtile[2][1024];   // 2 x 16 KB  raw int32 (128 rows x 8 chunks)

  const int tid = threadIdx.x;
  const int l   = tid & 63;
  const int w   = tid >> 6;
  const int l15 = l & 15;
  const int lk  = l >> 4;            // 0..3
  const int n0  = blockIdx.x * 128;
  const int ks  = blockIdx.y;
  const int k0  = ks * KCHUNK;

  const int r0 = n0 + w * 32 + l15;  // lane's two weight rows (B-frag cols)
  const int r1 = r0 + 16;

  // ---- scale/zp preload: 8 VMEM loads, retired before the loop ----
  const float* sp0 = scale + r0 * NGRP + ks * 8;
  const float* zp0 = zpt   + r0 * NGRP + ks * 8;
  const float* sp1 = scale + r1 * NGRP + ks * 8;
  const float* zp1 = zpt   + r1 * NGRP + ks * 8;
  float4 s0a = *(const float4*)sp0,     s0b = *(const float4*)(sp0 + 4);
  float4 z0a = *(const float4*)zp0,     z0b = *(const float4*)(zp0 + 4);
  float4 s1a = *(const float4*)sp1,     s1b = *(const float4*)(sp1 + 4);
  float4 z1a = *(const float4*)zp1,     z1b = *(const float4*)(zp1 + 4);

  // stage x+W tile t into LDS buffer nb: 4+4 global_load_lds (fire-and-forget)
  auto STAGE = [&](int t, int nb) {
    const int kt = k0 + t * BK;
    #pragma unroll
    for (int i = 0; i < 4; ++i) {                 // x: 16 KB
      int c = i * 256 + tid;                      // chunk 0..1023
      int row = c >> 3, q = (c & 7) ^ (row & 7);  // inverse swizzle on source
      const unsigned short* src = xb + (size_t)row * K_DIM + kt + q * 8;
      uint4* dst = &xtile[nb][i * 256 + w * 64];  // wave-uniform base
      __builtin_amdgcn_global_load_lds(
          (__attribute__((address_space(1))) void*)(void*)src,
          (__attribute__((address_space(3))) void*)(void*)dst, 16, 0, 0);
    }
    #pragma unroll
    for (int i = 0; i < 4; ++i) {                 // W raw: 16 KB (128 rows x 128B)
      int c = i * 256 + tid;
      int row = c >> 3, q = (c & 7) ^ (row & 7);
      const int* src = wq + (size_t)(n0 + row) * KP + (k0 >> 1) + t * 32 + q * 4;
      uint4* dst = &wtile[nb][i * 256 + w * 64];
      __builtin_amdgcn_global_load_lds(
          (__attribute__((address_space(1))) void*)(void*)src,
          (__attribute__((address_space(3))) void*)(void*)dst, 16, 0, 0);
    }
  };

  f32x4 acc[8][2];
  #pragma unroll
  for (int mi = 0; mi < 8; ++mi)
    #pragma unroll
    for (int ni = 0; ni < 2; ++ni) {
      f32x4 z = {0.f, 0.f, 0.f, 0.f};
      acc[mi][ni] = z;
    }

  // prologue: stage(0), stage(1); THEN derive scale regs (compiler's wait here
  // retires the 8 scale loads while keeping the 16 stage ops in flight)
  STAGE(0, 0);
  STAGE(1, 1);
  float scs0[8] = {s0a.x, s0a.y, s0a.z, s0a.w, s0b.x, s0b.y, s0b.z, s0b.w};
  float scs1[8] = {s1a.x, s1a.y, s1a.z, s1a.w, s1b.x, s1b.y, s1b.z, s1b.w};
  float nzs0[8] = {-z0a.x * s0a.x, -z0a.y * s0a.y, -z0a.z * s0a.z, -z0a.w * s0a.w,
                   -z0b.x * s0b.x, -z0b.y * s0b.y, -z0b.z * s0b.z, -z0b.w * s0b.w};
  float nzs1[8] = {-z1a.x * s1a.x, -z1a.y * s1a.y, -z1a.z * s1a.z, -z1a.w * s1a.w,
                   -z1b.x * s1b.x, -z1b.y * s1b.y, -z1b.z * s1b.z, -z1b.w * s1b.w};

  const int wrow0 = w * 32 + l15;          // local W rows in the 128-row tile
  const int wrow1 = wrow0 + 16;

  #pragma unroll
  for (int t = 0; t < NSTEPS; ++t) {
    // retire stage(t) exactly (keep stage(t+1)'s 8 in flight), then sync
    asm volatile("s_waitcnt vmcnt(8)" ::: "memory");
    __builtin_amdgcn_s_barrier();

    const int cb = t & 1;
    const float sc[2] = {scs0[t >> 1], scs1[t >> 1]};   // static after unroll
    const float nz[2] = {nzs0[t >> 1], nzs1[t >> 1]};

    #pragma unroll
    for (int kk = 0; kk < 2; ++kk) {
      const int q = kk * 4 + lk;
      uint4 av[8];
      #pragma unroll
      for (int mi = 0; mi < 8; ++mi) {
        int r = mi * 16 + l15;
        av[mi] = xtile[cb][r * 8 + (q ^ (r & 7))];
      }
      uint4 pw[2];
      pw[0] = wtile[cb][wrow0 * 8 + (q ^ (wrow0 & 7))];  // 4 ints = lane's 8 nibbles
      pw[1] = wtile[cb][wrow1 * 8 + (q ^ (wrow1 & 7))];
      uint4 bq[2];
      #pragma unroll
      for (int ni = 0; ni < 2; ++ni) {
        int v4[4] = {(int)pw[ni].x, (int)pw[ni].y, (int)pw[ni].z, (int)pw[ni].w};
        unsigned words[4];
        #pragma unroll
        for (int j = 0; j < 4; ++j) {
          int hi = (v4[j] << 24) >> 28;      // bits 7:4 -> k even (proven)
          int lo = (v4[j] << 28) >> 28;      // bits 3:0 -> k odd
          float fh = fmaf((float)hi, sc[ni], nz[ni]);
          float fl = fmaf((float)lo, sc[ni], nz[ni]);
          asm("v_cvt_pk_bf16_f32 %0, %1, %2" : "=v"(words[j]) : "v"(fh), "v"(fl));
        }
        uint4 o; o.x = words[0]; o.y = words[1]; o.z = words[2]; o.w = words[3];
        bq[ni] = o;
      }
      #pragma unroll
      for (int mi = 0; mi < 8; ++mi)
        #pragma unroll
        for (int ni = 0; ni < 2; ++ni)
          acc[mi][ni] = __builtin_amdgcn_mfma_f32_16x16x32_bf16(
              __builtin_bit_cast(bf16x8, av[mi]),
              __builtin_bit_cast(bf16x8, bq[ni]),
              acc[mi][ni], 0, 0, 0);
    }

    // WAR fence for buffer t&1, then refill it (count-uniform tail restage)
    __builtin_amdgcn_s_barrier();
    STAGE(t + 2 < NSTEPS ? t + 2 : NSTEPS - 1, t & 1);
  }
  asm volatile("s_waitcnt vmcnt(0)" ::: "memory");  // drain tail stages pre-epilogue

  // epilogue: fp32 atomic accumulate into out[s][o] (bias prefilled by xcast)
  #pragma unroll
  for (int mi = 0; mi < 8; ++mi)
    #pragma unroll
    for (int ni = 0; ni < 2; ++ni) {
      int col = n0 + w * 32 + ni * 16 + l15;
      int rowb = mi * 16 + lk * 4;
      #pragma unroll
      for (int j = 0; j < 4; ++j)
        atomicAdd(out + (size_t)(rowb + j) * N_DIM + col, acc[mi][ni][j]);
    }
}

extern "C" void kernel_launch(void* const* d_in, const int* in_sizes, int n_in,
                              void* d_out, int out_size, void* d_ws, size_t ws_size,
                              hipStream_t stream) {
  const float* x     = (const float*)d_in[0];
  const int*   wq    = (const int*)d_in[1];
  const float* scale = (const float*)d_in[2];
  const float* zpt   = (const float*)d_in[3];
  const float* bias  = (const float*)d_in[4];
  float* out = (float*)d_out;

  unsigned short* xb = (unsigned short*)d_ws;   // 2 MiB bf16 x

  xcast_kernel<<<(M_DIM * K_DIM) / (256 * 8), 256, 0, stream>>>(x, xb, bias, out);
  gemm_kernel<<<dim3(N_DIM / 128, KSPLIT), 256, 0, stream>>>(
      xb, wq, scale, zpt, out);
}

// Round 15
// 46.448 us; speedup vs baseline: 1.2466x; 1.2466x over previous
//
#include <hip/hip_runtime.h>
#include <hip/hip_bf16.h>
#include <stdint.h>

#define M_DIM 128
#define N_DIM 8192
#define K_DIM 8192
#define KP    4096      // packed int32 per weight row
#define NGRP  64
#define KSPLIT 8
#define KCHUNK (K_DIM / KSPLIT)   // 1024
#define BK    64
#define NSTEPS (KCHUNK / BK)      // 16

typedef __attribute__((ext_vector_type(8))) short bf16x8;
typedef __attribute__((ext_vector_type(4))) float f32x4;

__device__ __forceinline__ unsigned short f2bf(float f) {
  unsigned int u = __float_as_uint(f);
  return (unsigned short)((u + 0x7fffu + ((u >> 16) & 1u)) >> 16);
}

__global__ void xcast_kernel(const float* __restrict__ x, unsigned short* __restrict__ xb) {
  int idx = (blockIdx.x * blockDim.x + threadIdx.x) * 8;
  const float4* xp = (const float4*)(x + idx);
  float4 a = xp[0], b = xp[1];
  uint4 o;
  o.x = (unsigned)f2bf(a.x) | ((unsigned)f2bf(a.y) << 16);
  o.y = (unsigned)f2bf(a.z) | ((unsigned)f2bf(a.w) << 16);
  o.z = (unsigned)f2bf(b.x) | ((unsigned)f2bf(b.y) << 16);
  o.w = (unsigned)f2bf(b.z) | ((unsigned)f2bf(b.w) << 16);
  *(uint4*)(xb + idx) = o;
}

// R10-verbatim main loop (champion): both streams via global_load_lds,
// double-buffered 64KB LDS, counted vmcnt(8) + raw barriers (never drain),
// scales preloaded, full unroll. Epilogue: TRANSPOSED bf16 partial [ks][o][s]
// -> each lane stores 16 x uint2 (4 bf16 along contiguous s) instead of
// 64 x 2B scalar stores.
__global__ __launch_bounds__(256, 2)
void gemm_kernel(const unsigned short* __restrict__ xb,
                 const int* __restrict__ wq,
                 const float* __restrict__ scale,
                 const float* __restrict__ zpt,
                 unsigned short* __restrict__ partial)
{
  __shared__ uint4 xtile[2][1024];   // 2 x 16 KB  (128 rows x 8 chunks, swizzled)
  __shared__ uint4 wtile[2][1024];   // 2 x 16 KB  raw int32 (128 rows x 8 chunks)

  const int tid = threadIdx.x;
  const int l   = tid & 63;
  const int w   = tid >> 6;
  const int l15 = l & 15;
  const int lk  = l >> 4;            // 0..3
  const int n0  = blockIdx.x * 128;
  const int ks  = blockIdx.y;
  const int k0  = ks * KCHUNK;

  const int r0 = n0 + w * 32 + l15;  // lane's two weight rows (B-frag cols)
  const int r1 = r0 + 16;

  // ---- scale/zp preload: 8 VMEM loads, retired before the loop ----
  const float* sp0 = scale + r0 * NGRP + ks * 8;
  const float* zp0 = zpt   + r0 * NGRP + ks * 8;
  const float* sp1 = scale + r1 * NGRP + ks * 8;
  const float* zp1 = zpt   + r1 * NGRP + ks * 8;
  float4 s0a = *(const float4*)sp0,     s0b = *(const float4*)(sp0 + 4);
  float4 z0a = *(const float4*)zp0,     z0b = *(const float4*)(zp0 + 4);
  float4 s1a = *(const float4*)sp1,     s1b = *(const float4*)(sp1 + 4);
  float4 z1a = *(const float4*)zp1,     z1b = *(const float4*)(zp1 + 4);

  // stage x+W tile t into LDS buffer nb: 4+4 global_load_lds (fire-and-forget)
  auto STAGE = [&](int t, int nb) {
    const int kt = k0 + t * BK;
    #pragma unroll
    for (int i = 0; i < 4; ++i) {                 // x: 16 KB
      int c = i * 256 + tid;                      // chunk 0..1023
      int row = c >> 3, q = (c & 7) ^ (row & 7);  // inverse swizzle on source
      const unsigned short* src = xb + (size_t)row * K_DIM + kt + q * 8;
      uint4* dst = &xtile[nb][i * 256 + w * 64];  // wave-uniform base
      __builtin_amdgcn_global_load_lds(
          (__attribute__((address_space(1))) void*)(void*)src,
          (__attribute__((address_space(3))) void*)(void*)dst, 16, 0, 0);
    }
    #pragma unroll
    for (int i = 0; i < 4; ++i) {                 // W raw: 16 KB (128 rows x 128B)
      int c = i * 256 + tid;
      int row = c >> 3, q = (c & 7) ^ (row & 7);
      const int* src = wq + (size_t)(n0 + row) * KP + (k0 >> 1) + t * 32 + q * 4;
      uint4* dst = &wtile[nb][i * 256 + w * 64];
      __builtin_amdgcn_global_load_lds(
          (__attribute__((address_space(1))) void*)(void*)src,
          (__attribute__((address_space(3))) void*)(void*)dst, 16, 0, 0);
    }
  };

  f32x4 acc[8][2];
  #pragma unroll
  for (int mi = 0; mi < 8; ++mi)
    #pragma unroll
    for (int ni = 0; ni < 2; ++ni) {
      f32x4 z = {0.f, 0.f, 0.f, 0.f};
      acc[mi][ni] = z;
    }

  // prologue: stage(0), stage(1); THEN derive scale regs
  STAGE(0, 0);
  STAGE(1, 1);
  float scs0[8] = {s0a.x, s0a.y, s0a.z, s0a.w, s0b.x, s0b.y, s0b.z, s0b.w};
  float scs1[8] = {s1a.x, s1a.y, s1a.z, s1a.w, s1b.x, s1b.y, s1b.z, s1b.w};
  float nzs0[8] = {-z0a.x * s0a.x, -z0a.y * s0a.y, -z0a.z * s0a.z, -z0a.w * s0a.w,
                   -z0b.x * s0b.x, -z0b.y * s0b.y, -z0b.z * s0b.z, -z0b.w * s0b.w};
  float nzs1[8] = {-z1a.x * s1a.x, -z1a.y * s1a.y, -z1a.z * s1a.z, -z1a.w * s1a.w,
                   -z1b.x * s1b.x, -z1b.y * s1b.y, -z1b.z * s1b.z, -z1b.w * s1b.w};

  const int wrow0 = w * 32 + l15;          // local W rows in the 128-row tile
  const int wrow1 = wrow0 + 16;

  #pragma unroll
  for (int t = 0; t < NSTEPS; ++t) {
    // retire stage(t) exactly (keep stage(t+1)'s 8 in flight), then sync
    asm volatile("s_waitcnt vmcnt(8)" ::: "memory");
    __builtin_amdgcn_s_barrier();

    const int cb = t & 1;
    const float sc[2] = {scs0[t >> 1], scs1[t >> 1]};   // static after unroll
    const float nz[2] = {nzs0[t >> 1], nzs1[t >> 1]};

    #pragma unroll
    for (int kk = 0; kk < 2; ++kk) {
      const int q = kk * 4 + lk;
      uint4 av[8];
      #pragma unroll
      for (int mi = 0; mi < 8; ++mi) {
        int r = mi * 16 + l15;
        av[mi] = xtile[cb][r * 8 + (q ^ (r & 7))];
      }
      uint4 pw[2];
      pw[0] = wtile[cb][wrow0 * 8 + (q ^ (wrow0 & 7))];  // 4 ints = lane's 8 nibbles
      pw[1] = wtile[cb][wrow1 * 8 + (q ^ (wrow1 & 7))];
      uint4 bq[2];
      #pragma unroll
      for (int ni = 0; ni < 2; ++ni) {
        int v4[4] = {(int)pw[ni].x, (int)pw[ni].y, (int)pw[ni].z, (int)pw[ni].w};
        unsigned words[4];
        #pragma unroll
        for (int j = 0; j < 4; ++j) {
          int hi = (v4[j] << 24) >> 28;      // bits 7:4 -> k even (proven)
          int lo = (v4[j] << 28) >> 28;      // bits 3:0 -> k odd
          float fh = fmaf((float)hi, sc[ni], nz[ni]);
          float fl = fmaf((float)lo, sc[ni], nz[ni]);
          asm("v_cvt_pk_bf16_f32 %0, %1, %2" : "=v"(words[j]) : "v"(fh), "v"(fl));
        }
        uint4 o; o.x = words[0]; o.y = words[1]; o.z = words[2]; o.w = words[3];
        bq[ni] = o;
      }
      #pragma unroll
      for (int mi = 0; mi < 8; ++mi)
        #pragma unroll
        for (int ni = 0; ni < 2; ++ni)
          acc[mi][ni] = __builtin_amdgcn_mfma_f32_16x16x32_bf16(
              __builtin_bit_cast(bf16x8, av[mi]),
              __builtin_bit_cast(bf16x8, bq[ni]),
              acc[mi][ni], 0, 0, 0);
    }

    // WAR fence for buffer t&1, then refill it (count-uniform tail restage)
    __builtin_amdgcn_s_barrier();
    STAGE(t + 2 < NSTEPS ? t + 2 : NSTEPS - 1, t & 1);
  }
  asm volatile("s_waitcnt vmcnt(0)" ::: "memory");  // drain tail stages

  // epilogue: TRANSPOSED bf16 partial [ks][o][s]; lane's 4 values (j=0..3)
  // are consecutive s -> one uint2 (4 bf16, 8B) per (mi,ni).
  unsigned short* p = partial + (size_t)ks * (N_DIM * M_DIM);
  #pragma unroll
  for (int mi = 0; mi < 8; ++mi)
    #pragma unroll
    for (int ni = 0; ni < 2; ++ni) {
      int o  = n0 + w * 32 + ni * 16 + l15;
      int sb = mi * 16 + lk * 4;
      f32x4 v = acc[mi][ni];
      unsigned w0, w1;
      asm("v_cvt_pk_bf16_f32 %0, %1, %2" : "=v"(w0) : "v"(v[0]), "v"(v[1]));
      asm("v_cvt_pk_bf16_f32 %0, %1, %2" : "=v"(w1) : "v"(v[2]), "v"(v[3]));
      uint2 st; st.x = w0; st.y = w1;      // low16 = s even (matches reduce unpack)
      *(uint2*)(p + (size_t)o * M_DIM + sb) = st;
    }
}

// transposing reduce: part[ks][o][s] (coalesced in s) -> out[s][o] via LDS.
// Block = 16 o-cols x all 128 s. Verified: coverage, alignment, bf16 bit-order.
__global__ void reduce_kernel(const unsigned short* __restrict__ part,
                              const float* __restrict__ bias,
                              float* __restrict__ out) {
  __shared__ float tile[16][132];
  const int t = threadIdx.x;
  const int o_loc = t >> 4;          // 0..15
  const int sg    = t & 15;          // 0..15
  const int o  = blockIdx.x * 16 + o_loc;
  const int s0 = sg * 8;

  float s[8];
  #pragma unroll
  for (int j = 0; j < 8; ++j) s[j] = 0.f;
  #pragma unroll
  for (int k = 0; k < KSPLIT; ++k) {
    uint4 v = *(const uint4*)(part + (size_t)k * (N_DIM * M_DIM) + (size_t)o * M_DIM + s0);
    unsigned ws[4] = {v.x, v.y, v.z, v.w};
    #pragma unroll
    for (int j = 0; j < 4; ++j) {
      s[2 * j]     += __uint_as_float((ws[j] & 0xffffu) << 16);   // s even
      s[2 * j + 1] += __uint_as_float(ws[j] & 0xffff0000u);       // s odd
    }
  }
  const float b = bias[o];
  #pragma unroll
  for (int j = 0; j < 8; ++j) tile[o_loc][s0 + j] = s[j] + b;
  __syncthreads();

  const int o4 = (t & 3) * 4;        // 0,4,8,12
  const int sr = t >> 2;             // 0..63
  #pragma unroll
  for (int rep = 0; rep < 2; ++rep) {
    int srow = sr + rep * 64;
    float4 ov;
    ov.x = tile[o4 + 0][srow];
    ov.y = tile[o4 + 1][srow];
    ov.z = tile[o4 + 2][srow];
    ov.w = tile[o4 + 3][srow];
    *(float4*)(out + (size_t)srow * N_DIM + blockIdx.x * 16 + o4) = ov;
  }
}

extern "C" void kernel_launch(void* const* d_in, const int* in_sizes, int n_in,
                              void* d_out, int out_size, void* d_ws, size_t ws_size,
                              hipStream_t stream) {
  const float* x     = (const float*)d_in[0];
  const int*   wq    = (const int*)d_in[1];
  const float* scale = (const float*)d_in[2];
  const float* zpt   = (const float*)d_in[3];
  const float* bias  = (const float*)d_in[4];
  float* out = (float*)d_out;

  unsigned short* xb = (unsigned short*)d_ws;
  const size_t xbytes = (size_t)M_DIM * K_DIM * 2;                   // 2 MiB
  unsigned short* partial = (unsigned short*)((char*)d_ws + xbytes); // 16 MiB bf16

  xcast_kernel<<<(M_DIM * K_DIM) / (256 * 8), 256, 0, stream>>>(x, xb);
  gemm_kernel<<<dim3(N_DIM / 128, KSPLIT), 256, 0, stream>>>(
      xb, wq, scale, zpt, partial);
  reduce_kernel<<<N_DIM / 16, 256, 0, stream>>>(partial, bias, out);
}

// Round 16
// 44.053 us; speedup vs baseline: 1.3144x; 1.0544x over previous
//
#include <hip/hip_runtime.h>
#include <hip/hip_bf16.h>
#include <stdint.h>

#define M_DIM 128
#define N_DIM 8192
#define K_DIM 8192
#define KP    4096      // packed int32 per weight row
#define NGRP  64
#define KSPLIT 8
#define KCHUNK (K_DIM / KSPLIT)   // 1024
#define BK    64
#define NSTEPS (KCHUNK / BK)      // 16

typedef __attribute__((ext_vector_type(8))) short bf16x8;
typedef __attribute__((ext_vector_type(4))) float f32x4;

__device__ __forceinline__ unsigned short f2bf(float f) {
  unsigned int u = __float_as_uint(f);
  return (unsigned short)((u + 0x7fffu + ((u >> 16) & 1u)) >> 16);
}

__global__ void xcast_kernel(const float* __restrict__ x, unsigned short* __restrict__ xb) {
  int idx = (blockIdx.x * blockDim.x + threadIdx.x) * 8;
  const float4* xp = (const float4*)(x + idx);
  float4 a = xp[0], b = xp[1];
  uint4 o;
  o.x = (unsigned)f2bf(a.x) | ((unsigned)f2bf(a.y) << 16);
  o.y = (unsigned)f2bf(a.z) | ((unsigned)f2bf(a.w) << 16);
  o.z = (unsigned)f2bf(b.x) | ((unsigned)f2bf(b.y) << 16);
  o.w = (unsigned)f2bf(b.z) | ((unsigned)f2bf(b.w) << 16);
  *(uint4*)(xb + idx) = o;
}

// Block 128(M)x128(N), 4 waves. BOTH streams via global_load_lds (fire-and-
// forget, allocator can't sink them). Double-buffered 64KB LDS, counted
// vmcnt(8) + raw barriers (never drain), all scales preloaded to regs,
// full unroll for static indexing. Dequant happens at ds_read time.
__global__ __launch_bounds__(256, 2)
void gemm_kernel(const unsigned short* __restrict__ xb,
                 const int* __restrict__ wq,
                 const float* __restrict__ scale,
                 const float* __restrict__ zpt,
                 unsigned short* __restrict__ partial)
{
  __shared__ uint4 xtile[2][1024];   // 2 x 16 KB  (128 rows x 8 chunks, swizzled)
  __shared__ uint4 wtile[2][1024];   // 2 x 16 KB  raw int32 (128 rows x 8 chunks)

  const int tid = threadIdx.x;
  const int l   = tid & 63;
  const int w   = tid >> 6;
  const int l15 = l & 15;
  const int lk  = l >> 4;            // 0..3
  const int n0  = blockIdx.x * 128;
  const int ks  = blockIdx.y;
  const int k0  = ks * KCHUNK;

  const int r0 = n0 + w * 32 + l15;  // lane's two weight rows (B-frag cols)
  const int r1 = r0 + 16;

  // ---- scale/zp preload: 8 VMEM loads, retired before the loop ----
  const float* sp0 = scale + r0 * NGRP + ks * 8;
  const float* zp0 = zpt   + r0 * NGRP + ks * 8;
  const float* sp1 = scale + r1 * NGRP + ks * 8;
  const float* zp1 = zpt   + r1 * NGRP + ks * 8;
  float4 s0a = *(const float4*)sp0,     s0b = *(const float4*)(sp0 + 4);
  float4 z0a = *(const float4*)zp0,     z0b = *(const float4*)(zp0 + 4);
  float4 s1a = *(const float4*)sp1,     s1b = *(const float4*)(sp1 + 4);
  float4 z1a = *(const float4*)zp1,     z1b = *(const float4*)(zp1 + 4);

  // stage x+W tile t into LDS buffer nb: 4+4 global_load_lds (fire-and-forget)
  auto STAGE = [&](int t, int nb) {
    const int kt = k0 + t * BK;
    #pragma unroll
    for (int i = 0; i < 4; ++i) {                 // x: 16 KB
      int c = i * 256 + tid;                      // chunk 0..1023
      int row = c >> 3, q = (c & 7) ^ (row & 7);  // inverse swizzle on source
      const unsigned short* src = xb + (size_t)row * K_DIM + kt + q * 8;
      uint4* dst = &xtile[nb][i * 256 + w * 64];  // wave-uniform base
      __builtin_amdgcn_global_load_lds(
          (__attribute__((address_space(1))) void*)(void*)src,
          (__attribute__((address_space(3))) void*)(void*)dst, 16, 0, 0);
    }
    #pragma unroll
    for (int i = 0; i < 4; ++i) {                 // W raw: 16 KB (128 rows x 128B)
      int c = i * 256 + tid;
      int row = c >> 3, q = (c & 7) ^ (row & 7);
      const int* src = wq + (size_t)(n0 + row) * KP + (k0 >> 1) + t * 32 + q * 4;
      uint4* dst = &wtile[nb][i * 256 + w * 64];
      __builtin_amdgcn_global_load_lds(
          (__attribute__((address_space(1))) void*)(void*)src,
          (__attribute__((address_space(3))) void*)(void*)dst, 16, 0, 0);
    }
  };

  f32x4 acc[8][2];
  #pragma unroll
  for (int mi = 0; mi < 8; ++mi)
    #pragma unroll
    for (int ni = 0; ni < 2; ++ni) {
      f32x4 z = {0.f, 0.f, 0.f, 0.f};
      acc[mi][ni] = z;
    }

  // prologue: stage(0), stage(1); THEN derive scale regs (compiler's wait here
  // retires the 8 scale loads while keeping the 16 stage ops in flight)
  STAGE(0, 0);
  STAGE(1, 1);
  float scs0[8] = {s0a.x, s0a.y, s0a.z, s0a.w, s0b.x, s0b.y, s0b.z, s0b.w};
  float scs1[8] = {s1a.x, s1a.y, s1a.z, s1a.w, s1b.x, s1b.y, s1b.z, s1b.w};
  float nzs0[8] = {-z0a.x * s0a.x, -z0a.y * s0a.y, -z0a.z * s0a.z, -z0a.w * s0a.w,
                   -z0b.x * s0b.x, -z0b.y * s0b.y, -z0b.z * s0b.z, -z0b.w * s0b.w};
  float nzs1[8] = {-z1a.x * s1a.x, -z1a.y * s1a.y, -z1a.z * s1a.z, -z1a.w * s1a.w,
                   -z1b.x * s1b.x, -z1b.y * s1b.y, -z1b.z * s1b.z, -z1b.w * s1b.w};

  const int wrow0 = w * 32 + l15;          // local W rows in the 128-row tile
  const int wrow1 = wrow0 + 16;

  #pragma unroll
  for (int t = 0; t < NSTEPS; ++t) {
    // retire stage(t) exactly (keep stage(t+1)'s 8 in flight), then sync
    asm volatile("s_waitcnt vmcnt(8)" ::: "memory");
    __builtin_amdgcn_s_barrier();

    const int cb = t & 1;
    const float sc[2] = {scs0[t >> 1], scs1[t >> 1]};   // static after unroll
    const float nz[2] = {nzs0[t >> 1], nzs1[t >> 1]};

    #pragma unroll
    for (int kk = 0; kk < 2; ++kk) {
      const int q = kk * 4 + lk;
      uint4 av[8];
      #pragma unroll
      for (int mi = 0; mi < 8; ++mi) {
        int r = mi * 16 + l15;
        av[mi] = xtile[cb][r * 8 + (q ^ (r & 7))];
      }
      uint4 pw[2];
      pw[0] = wtile[cb][wrow0 * 8 + (q ^ (wrow0 & 7))];  // 4 ints = lane's 8 nibbles
      pw[1] = wtile[cb][wrow1 * 8 + (q ^ (wrow1 & 7))];
      uint4 bq[2];
      #pragma unroll
      for (int ni = 0; ni < 2; ++ni) {
        int v4[4] = {(int)pw[ni].x, (int)pw[ni].y, (int)pw[ni].z, (int)pw[ni].w};
        unsigned words[4];
        #pragma unroll
        for (int j = 0; j < 4; ++j) {
          int hi = (v4[j] << 24) >> 28;      // bits 7:4 -> k even (R4-proven)
          int lo = (v4[j] << 28) >> 28;      // bits 3:0 -> k odd
          float fh = fmaf((float)hi, sc[ni], nz[ni]);
          float fl = fmaf((float)lo, sc[ni], nz[ni]);
          asm("v_cvt_pk_bf16_f32 %0, %1, %2" : "=v"(words[j]) : "v"(fh), "v"(fl));
        }
        uint4 o; o.x = words[0]; o.y = words[1]; o.z = words[2]; o.w = words[3];
        bq[ni] = o;
      }
      #pragma unroll
      for (int mi = 0; mi < 8; ++mi)
        #pragma unroll
        for (int ni = 0; ni < 2; ++ni)
          acc[mi][ni] = __builtin_amdgcn_mfma_f32_16x16x32_bf16(
              __builtin_bit_cast(bf16x8, av[mi]),
              __builtin_bit_cast(bf16x8, bq[ni]),
              acc[mi][ni], 0, 0, 0);
    }

    // WAR fence for buffer t&1, then refill it (count-uniform tail restage)
    __builtin_amdgcn_s_barrier();
    STAGE(t + 2 < NSTEPS ? t + 2 : NSTEPS - 1, t & 1);
  }
  asm volatile("s_waitcnt vmcnt(0)" ::: "memory");  // drain tail stages pre-endpgm

  // epilogue: bf16 partial [ks][s][o] (R4-verbatim)
  unsigned short* p = partial + (size_t)ks * (M_DIM * N_DIM);
  #pragma unroll
  for (int mi = 0; mi < 8; ++mi)
    #pragma unroll
    for (int ni = 0; ni < 2; ++ni) {
      int col = n0 + w * 32 + ni * 16 + l15;
      int rowb = mi * 16 + lk * 4;
      #pragma unroll
      for (int j = 0; j < 4; ++j)
        p[(size_t)(rowb + j) * N_DIM + col] = f2bf(acc[mi][ni][j]);
    }
}

// reduce over ksplit + bias (R4-verbatim)
__global__ void reduce_kernel(const unsigned short* __restrict__ part,
                              const float* __restrict__ bias,
                              float* __restrict__ out) {
  int idx = (blockIdx.x * blockDim.x + threadIdx.x) * 8;
  float s[8];
  #pragma unroll
  for (int j = 0; j < 8; ++j) s[j] = 0.f;
  #pragma unroll
  for (int k = 0; k < KSPLIT; ++k) {
    uint4 v = *(const uint4*)(part + (size_t)k * (M_DIM * N_DIM) + idx);
    unsigned ws[4] = {v.x, v.y, v.z, v.w};
    #pragma unroll
    for (int j = 0; j < 4; ++j) {
      s[2 * j]     += __uint_as_float((ws[j] & 0xffffu) << 16);
      s[2 * j + 1] += __uint_as_float(ws[j] & 0xffff0000u);
    }
  }
  int col = idx & (N_DIM - 1);
  float4 b0 = *(const float4*)(bias + col);
  float4 b1 = *(const float4*)(bias + col + 4);
  float4 o0, o1;
  o0.x = s[0] + b0.x; o0.y = s[1] + b0.y; o0.z = s[2] + b0.z; o0.w = s[3] + b0.w;
  o1.x = s[4] + b1.x; o1.y = s[5] + b1.y; o1.z = s[6] + b1.z; o1.w = s[7] + b1.w;
  *(float4*)(out + idx) = o0;
  *(float4*)(out + idx + 4) = o1;
}

extern "C" void kernel_launch(void* const* d_in, const int* in_sizes, int n_in,
                              void* d_out, int out_size, void* d_ws, size_t ws_size,
                              hipStream_t stream) {
  const float* x     = (const float*)d_in[0];
  const int*   wq    = (const int*)d_in[1];
  const float* scale = (const float*)d_in[2];
  const float* zpt   = (const float*)d_in[3];
  const float* bias  = (const float*)d_in[4];
  float* out = (float*)d_out;

  unsigned short* xb = (unsigned short*)d_ws;
  const size_t xbytes = (size_t)M_DIM * K_DIM * 2;                   // 2 MiB
  unsigned short* partial = (unsigned short*)((char*)d_ws + xbytes); // 16 MiB bf16

  xcast_kernel<<<(M_DIM * K_DIM) / (256 * 8), 256, 0, stream>>>(x, xb);
  gemm_kernel<<<dim3(N_DIM / 128, KSPLIT), 256, 0, stream>>>(
      xb, wq, scale, zpt, partial);
  reduce_kernel<<<(M_DIM * N_DIM) / (256 * 8), 256, 0, stream>>>(
      partial, bias, out);
}